// Round 6
// baseline (238.159 us; speedup 1.0000x reference)
//
#include <hip/hip_runtime.h>
#include <hip/hip_bf16.h>

// Problem constants
#define HH 40
#define WW 40
#define KK 5
#define PP 1296            // 36*36
#define LL 25
#define MM 384
#define NN 64
#define NPTS (NN * PP)     // 82944
#define JITTER 1e-6f

typedef unsigned short u16;
typedef unsigned int   u32;
using short8  = __attribute__((ext_vector_type(8))) short;
using floatx4 = __attribute__((ext_vector_type(4))) float;

#define FRAG_N (MM * MM)        // u16 per frag half-array (147456)
#define ZFRAG_N (24 * 64 * 8)   // 12288

// ---------------------------------------------------------------------------
// bf16 split helpers (RNE)
__device__ inline u16 f2bf(float v) {
    u32 b = __float_as_uint(v);
    return (u16)((b + 0x7FFFu + ((b >> 16) & 1u)) >> 16);
}
__device__ inline float bf2f(u16 h) { return __uint_as_float(((u32)h) << 16); }
__device__ inline void split_bf16(float v, u16& hi, u16& lo) {
    hi = f2bf(v);
    lo = f2bf(v - bf2f(hi));
}

// A-fragment linear index (u16 units) for element (m,k), HW-verified rounds 2-5.
__device__ inline int frag_idx(int m, int k) {
    return (((m >> 4) * 12 + (k >> 5)) * 64 + ((m & 15) + (((k >> 3) & 3) << 4))) * 8 + (k & 7);
}

// ---------------------------------------------------------------------------
// Split-bf16 MFMA 64x64-tile GEMM on A-frag operands: C = A . B^T_storage.
__device__ inline void frag_gemm64(const u16* __restrict__ Ah, const u16* __restrict__ Al,
                                   const u16* __restrict__ Bh, const u16* __restrict__ Bl,
                                   int bi, int bj, int w, int l, floatx4 acc[2][2]) {
    int mt0 = bi * 4 + 2 * (w & 1);
    int nt0 = bj * 4 + 2 * (w >> 1);
#pragma unroll
    for (int i = 0; i < 2; ++i)
#pragma unroll
        for (int jn = 0; jn < 2; ++jn) { floatx4 z = {0.f, 0.f, 0.f, 0.f}; acc[i][jn] = z; }
    for (int kt = 0; kt < 12; ++kt) {
        int ab0 = (((mt0 + 0) * 12 + kt) * 64 + l) * 8;
        int ab1 = (((mt0 + 1) * 12 + kt) * 64 + l) * 8;
        int bb0 = (((nt0 + 0) * 12 + kt) * 64 + l) * 8;
        int bb1 = (((nt0 + 1) * 12 + kt) * 64 + l) * 8;
        short8 a0h = *(const short8*)&Ah[ab0];
        short8 a0l = *(const short8*)&Al[ab0];
        short8 a1h = *(const short8*)&Ah[ab1];
        short8 a1l = *(const short8*)&Al[ab1];
        short8 b0h = *(const short8*)&Bh[bb0];
        short8 b0l = *(const short8*)&Bl[bb0];
        short8 b1h = *(const short8*)&Bh[bb1];
        short8 b1l = *(const short8*)&Bl[bb1];
        acc[0][0] = __builtin_amdgcn_mfma_f32_16x16x32_bf16(a0h, b0h, acc[0][0], 0, 0, 0);
        acc[0][0] = __builtin_amdgcn_mfma_f32_16x16x32_bf16(a0h, b0l, acc[0][0], 0, 0, 0);
        acc[0][0] = __builtin_amdgcn_mfma_f32_16x16x32_bf16(a0l, b0h, acc[0][0], 0, 0, 0);
        acc[0][1] = __builtin_amdgcn_mfma_f32_16x16x32_bf16(a0h, b1h, acc[0][1], 0, 0, 0);
        acc[0][1] = __builtin_amdgcn_mfma_f32_16x16x32_bf16(a0h, b1l, acc[0][1], 0, 0, 0);
        acc[0][1] = __builtin_amdgcn_mfma_f32_16x16x32_bf16(a0l, b1h, acc[0][1], 0, 0, 0);
        acc[1][0] = __builtin_amdgcn_mfma_f32_16x16x32_bf16(a1h, b0h, acc[1][0], 0, 0, 0);
        acc[1][0] = __builtin_amdgcn_mfma_f32_16x16x32_bf16(a1h, b0l, acc[1][0], 0, 0, 0);
        acc[1][0] = __builtin_amdgcn_mfma_f32_16x16x32_bf16(a1l, b0h, acc[1][0], 0, 0, 0);
        acc[1][1] = __builtin_amdgcn_mfma_f32_16x16x32_bf16(a1h, b1h, acc[1][1], 0, 0, 0);
        acc[1][1] = __builtin_amdgcn_mfma_f32_16x16x32_bf16(a1h, b1l, acc[1][1], 0, 0, 0);
        acc[1][1] = __builtin_amdgcn_mfma_f32_16x16x32_bf16(a1l, b1h, acc[1][1], 0, 0, 0);
    }
}

__device__ inline void dwrite_frag(u16* __restrict__ Oh, u16* __restrict__ Ol,
                                   int m, int p, float v) {
    int idx = frag_idx(m, p);
    u16 hi, lo;
    split_bf16(v, hi, lo);
    Oh[idx] = hi; Ol[idx] = lo;
}

// R0 = I - alpha*Kuu fragment built on the fly (R0 symmetric)
__device__ inline void load_r0(const float* __restrict__ Kuu, float alpha,
                               int row, int kt, int l, short8& h8, short8& l8) {
    int kb = kt * 32 + ((l >> 4) << 3);
    const float* p = &Kuu[row * MM + kb];
    float4 f0 = *(const float4*)p;
    float4 f1 = *(const float4*)(p + 4);
    float vv[8] = {f0.x, f0.y, f0.z, f0.w, f1.x, f1.y, f1.z, f1.w};
#pragma unroll
    for (int j = 0; j < 8; ++j) {
        float r = ((row == kb + j) ? 1.f : 0.f) - alpha * vv[j];
        u16 h, lo;
        split_bf16(r, h, lo);
        h8[j] = (short)h; l8[j] = (short)lo;
    }
}

// ---------------------------------------------------------------------------
// Launch 1: Kuu + rowsums + z2 + Z frags + Qt frags (A-frag of Q^T).
__global__ void __launch_bounds__(384) prep_kernel(
    const float* __restrict__ Z, const float* __restrict__ q_sqrt,
    const float* __restrict__ var_p, const float* __restrict__ ls_p,
    float* __restrict__ Kuu, float* __restrict__ rsum, float* __restrict__ z2g,
    u16* __restrict__ Qth, u16* __restrict__ Qtl,
    u16* __restrict__ Zfh, u16* __restrict__ Zfl) {
    __shared__ float Zs[LL];
    __shared__ float red[384];
    int r = blockIdx.x, tid = threadIdx.x;
    if (tid < LL) Zs[tid] = Z[r * LL + tid];
    __syncthreads();
    float var = var_p[0];
    float ls = ls_p[0];
    float c0 = -0.5f / (ls * ls);
    float s = 0.f;
#pragma unroll
    for (int d = 0; d < LL; ++d) {
        float dd = Zs[d] - Z[tid * LL + d];
        s += dd * dd;
    }
    float v = var * expf(c0 * s);
    if (tid == r) v += JITTER;
    Kuu[r * MM + tid] = v;
    red[tid] = v;
    __syncthreads();
    if (tid < 128) red[tid] += red[tid + 256];
    __syncthreads();
    for (int o = 128; o > 0; o >>= 1) {
        if (tid < o) red[tid] += red[tid + o];
        __syncthreads();
    }
    if (tid == 0) {
        rsum[r] = red[0];
        float t = 0.f;
#pragma unroll
        for (int d = 0; d < LL; ++d) t += Zs[d] * Zs[d];
        z2g[r] = t;
    }
    // Qt frags (one element per thread): value = Q^T[m,k] = tril(q_sqrt)[k,m]
    {
        int o = r * MM + tid;
        int j = o & 7, ln = (o >> 3) & 63, kt = (o >> 9) % 12, mt = o / 6144;
        int m = mt * 16 + (ln & 15);
        int k = kt * 32 + ((ln >> 4) << 3) + j;
        float qv = (m <= k) ? q_sqrt[k * MM + m] : 0.f;
        u16 h, lo;
        split_bf16(qv, h, lo);
        Qth[o] = h; Qtl[o] = lo;
        if (o < ZFRAG_N) {
            int zt = o >> 9;
            int mz = zt * 16 + (ln & 15);
            int kd = ((ln >> 4) << 3) + j;
            float zv = (kd < LL) ? Z[mz * LL + kd] : 0.f;
            split_bf16(zv, h, lo);
            Zfh[o] = h; Zfl[o] = lo;
        }
    }
}

// ---------------------------------------------------------------------------
// Launch 2: blocks 0-35: X1 = alpha*(2I - alpha*Kuu); blocks 36-71: R1 = R0@R0.
__global__ void __launch_bounds__(256) ns1_kernel(
    const float* __restrict__ Kuu, const float* __restrict__ rsum,
    u16* __restrict__ Xh, u16* __restrict__ Xl,
    u16* __restrict__ Rh, u16* __restrict__ Rl) {
    __shared__ float red[256];
    int tid = threadIdx.x, blk = blockIdx.x;
    int w = tid >> 6, l = tid & 63;
    float v0 = rsum[tid];
    if (tid < 128) v0 = fmaxf(v0, rsum[tid + 256]);
    red[tid] = v0;
    __syncthreads();
    for (int o = 128; o > 0; o >>= 1) {
        if (tid < o) red[tid] = fmaxf(red[tid], red[tid + o]);
        __syncthreads();
    }
    float alpha = 1.0f / red[0];
    if (blk < 36) {
        float a2 = alpha * alpha;
        for (int o = blk * 256 + tid; o < FRAG_N; o += 36 * 256) {
            int j = o & 7, ln = (o >> 3) & 63, kt = (o >> 9) % 12, mt = o / 6144;
            int m = mt * 16 + (ln & 15);
            int k = kt * 32 + ((ln >> 4) << 3) + j;
            float v = ((m == k) ? 2.f * alpha : 0.f) - a2 * Kuu[m * MM + k];
            u16 h, lo;
            split_bf16(v, h, lo);
            Xh[o] = h; Xl[o] = lo;
        }
    } else {
        int tile = blk - 36;
        int bi = tile / 6, bj = tile % 6;
        int mt0 = bi * 4 + 2 * (w & 1), nt0 = bj * 4 + 2 * (w >> 1);
        floatx4 acc[2][2];
#pragma unroll
        for (int i = 0; i < 2; ++i)
#pragma unroll
            for (int jn = 0; jn < 2; ++jn) { floatx4 z = {0.f,0.f,0.f,0.f}; acc[i][jn] = z; }
        for (int kt = 0; kt < 12; ++kt) {
            short8 a0h, a0l, a1h, a1l, b0h, b0l, b1h, b1l;
            load_r0(Kuu, alpha, (mt0 + 0) * 16 + (l & 15), kt, l, a0h, a0l);
            load_r0(Kuu, alpha, (mt0 + 1) * 16 + (l & 15), kt, l, a1h, a1l);
            load_r0(Kuu, alpha, (nt0 + 0) * 16 + (l & 15), kt, l, b0h, b0l);
            load_r0(Kuu, alpha, (nt0 + 1) * 16 + (l & 15), kt, l, b1h, b1l);
            acc[0][0] = __builtin_amdgcn_mfma_f32_16x16x32_bf16(a0h, b0h, acc[0][0], 0, 0, 0);
            acc[0][0] = __builtin_amdgcn_mfma_f32_16x16x32_bf16(a0h, b0l, acc[0][0], 0, 0, 0);
            acc[0][0] = __builtin_amdgcn_mfma_f32_16x16x32_bf16(a0l, b0h, acc[0][0], 0, 0, 0);
            acc[0][1] = __builtin_amdgcn_mfma_f32_16x16x32_bf16(a0h, b1h, acc[0][1], 0, 0, 0);
            acc[0][1] = __builtin_amdgcn_mfma_f32_16x16x32_bf16(a0h, b1l, acc[0][1], 0, 0, 0);
            acc[0][1] = __builtin_amdgcn_mfma_f32_16x16x32_bf16(a0l, b1h, acc[0][1], 0, 0, 0);
            acc[1][0] = __builtin_amdgcn_mfma_f32_16x16x32_bf16(a1h, b0h, acc[1][0], 0, 0, 0);
            acc[1][0] = __builtin_amdgcn_mfma_f32_16x16x32_bf16(a1h, b0l, acc[1][0], 0, 0, 0);
            acc[1][0] = __builtin_amdgcn_mfma_f32_16x16x32_bf16(a1l, b0h, acc[1][0], 0, 0, 0);
            acc[1][1] = __builtin_amdgcn_mfma_f32_16x16x32_bf16(a1h, b1h, acc[1][1], 0, 0, 0);
            acc[1][1] = __builtin_amdgcn_mfma_f32_16x16x32_bf16(a1h, b1l, acc[1][1], 0, 0, 0);
            acc[1][1] = __builtin_amdgcn_mfma_f32_16x16x32_bf16(a1l, b1h, acc[1][1], 0, 0, 0);
        }
#pragma unroll
        for (int i = 0; i < 2; ++i)
#pragma unroll
            for (int jn = 0; jn < 2; ++jn)
#pragma unroll
                for (int j = 0; j < 4; ++j) {
                    int m = (mt0 + i) * 16 + ((l >> 4) << 2) + j;
                    int p = (nt0 + jn) * 16 + (l & 15);
                    dwrite_frag(Rh, Rl, m, p, acc[i][jn][j]);
                }
    }
}

// ---------------------------------------------------------------------------
// NS rounds: blocks 0-35: X' = X + X@R ; 36-71: R' = R@R
__global__ void __launch_bounds__(256) ns_kernel(
    const u16* __restrict__ cxh, const u16* __restrict__ cxl,
    const u16* __restrict__ crh, const u16* __restrict__ crl,
    u16* __restrict__ nxh, u16* __restrict__ nxl,
    u16* __restrict__ nrh, u16* __restrict__ nrl) {
    int blk = blockIdx.x, tid = threadIdx.x;
    bool isX = (blk < 36);
    int tile = isX ? blk : blk - 36;
    int bi = tile / 6, bj = tile % 6;
    int w = tid >> 6, l = tid & 63;
    floatx4 acc[2][2];
    frag_gemm64(isX ? cxh : crh, isX ? cxl : crl, crh, crl, bi, bj, w, l, acc);
    int mt0 = bi * 4 + 2 * (w & 1), nt0 = bj * 4 + 2 * (w >> 1);
    u16* Oh = isX ? nxh : nrh;
    u16* Ol = isX ? nxl : nrl;
#pragma unroll
    for (int i = 0; i < 2; ++i)
#pragma unroll
        for (int jn = 0; jn < 2; ++jn)
#pragma unroll
            for (int j = 0; j < 4; ++j) {
                int m = (mt0 + i) * 16 + ((l >> 4) << 2) + j;
                int p = (nt0 + jn) * 16 + (l & 15);
                float v = acc[i][jn][j];
                if (isX) {
                    int id = frag_idx(m, p);
                    v += bf2f(cxh[id]) + bf2f(cxl[id]);
                }
                dwrite_frag(Oh, Ol, m, p, v);
            }
}

// ---------------------------------------------------------------------------
// Fused launch: blocks 0-35: Bq[bi,bj] = (G G^T - X)[tile], G = X @ tril(q_sqrt)
//   via G^T = Q^T X tiles computed into LDS A-frag panels (register-axis trick).
// blocks 36-38: cvec = X @ q_mu (8 waves -> 8 m-tiles each).
__global__ void __launch_bounds__(512) gbq_kernel(
    const u16* __restrict__ Xh, const u16* __restrict__ Xl,
    const u16* __restrict__ Qth, const u16* __restrict__ Qtl,
    const float* __restrict__ qmu,
    u16* __restrict__ Bqh, u16* __restrict__ Bql, float* __restrict__ cvec) {
    __shared__ u16 pAh[4 * 12 * 64 * 8];   // G[bi-rows] panel, hi  (48 KB)
    __shared__ u16 pAl[4 * 12 * 64 * 8];   // lo                    (48 KB)
    __shared__ u16 pBh[4 * 12 * 64 * 8];   // G[bj-rows] panel, hi  (48 KB)
    __shared__ float qbuf[MM];
    int tid = threadIdx.x, blk = blockIdx.x;
    int w = tid >> 6, l = tid & 63;
    if (blk < 36) {
        int bi = blk / 6, bj = blk % 6;
        int wg = w >> 2, wl = w & 3;
        int u = l >> 4;
#pragma unroll
        for (int side = 0; side < 2; ++side) {
            int rowblk = (side == 0) ? bi : bj;
            for (int pp = 0; pp < 3; ++pp) {
                int t = pp * 2 + wg;   // G^T k-block tile 0..5
                floatx4 acc[2][2];
                frag_gemm64(Qth, Qtl, Xh, Xl, t, rowblk, wl, l, acc);
                // store D (rows = k of G, cols = rows of G) into panel A-frag
#pragma unroll
                for (int i = 0; i < 2; ++i) {
                    int k16 = t * 4 + 2 * (wl & 1) + i;   // 16-row group of k
                    int kt = k16 >> 1;
                    int rr = 2 * (k16 & 1) + (u >> 1);
#pragma unroll
                    for (int jn = 0; jn < 2; ++jn) {
                        int mt_loc = 2 * (wl >> 1) + jn;  // local m-tile 0..3
                        int base = ((mt_loc * 12 + kt) * 64 + rr * 16 + (l & 15)) * 8 + 4 * (u & 1);
                        u16 hi[4], lo[4];
#pragma unroll
                        for (int j = 0; j < 4; ++j) split_bf16(acc[i][jn][j], hi[j], lo[j]);
                        if (side == 0) {
                            *(u32*)&pAh[base]     = (u32)hi[0] | ((u32)hi[1] << 16);
                            *(u32*)&pAh[base + 2] = (u32)hi[2] | ((u32)hi[3] << 16);
                            *(u32*)&pAl[base]     = (u32)lo[0] | ((u32)lo[1] << 16);
                            *(u32*)&pAl[base + 2] = (u32)lo[2] | ((u32)lo[3] << 16);
                        } else {
                            *(u32*)&pBh[base]     = (u32)hi[0] | ((u32)hi[1] << 16);
                            *(u32*)&pBh[base + 2] = (u32)hi[2] | ((u32)hi[3] << 16);
                        }
                    }
                }
            }
        }
        __syncthreads();
        if (w < 4) {
            // final: Bq tile = panelA . panelB^T - X  (2-term: Ah.Bh + Al.Bh)
            floatx4 fac[2][2];
#pragma unroll
            for (int i = 0; i < 2; ++i)
#pragma unroll
                for (int jn = 0; jn < 2; ++jn) { floatx4 z = {0.f,0.f,0.f,0.f}; fac[i][jn] = z; }
            int mt0 = 2 * (w & 1), nt0 = 2 * (w >> 1);
            for (int kt = 0; kt < 12; ++kt) {
                int a0 = (((mt0 + 0) * 12 + kt) * 64 + l) * 8;
                int a1 = (((mt0 + 1) * 12 + kt) * 64 + l) * 8;
                int b0 = (((nt0 + 0) * 12 + kt) * 64 + l) * 8;
                int b1 = (((nt0 + 1) * 12 + kt) * 64 + l) * 8;
                short8 a0h = *(const short8*)&pAh[a0];
                short8 a0l = *(const short8*)&pAl[a0];
                short8 a1h = *(const short8*)&pAh[a1];
                short8 a1l = *(const short8*)&pAl[a1];
                short8 b0h = *(const short8*)&pBh[b0];
                short8 b1h = *(const short8*)&pBh[b1];
                fac[0][0] = __builtin_amdgcn_mfma_f32_16x16x32_bf16(a0h, b0h, fac[0][0], 0, 0, 0);
                fac[0][0] = __builtin_amdgcn_mfma_f32_16x16x32_bf16(a0l, b0h, fac[0][0], 0, 0, 0);
                fac[0][1] = __builtin_amdgcn_mfma_f32_16x16x32_bf16(a0h, b1h, fac[0][1], 0, 0, 0);
                fac[0][1] = __builtin_amdgcn_mfma_f32_16x16x32_bf16(a0l, b1h, fac[0][1], 0, 0, 0);
                fac[1][0] = __builtin_amdgcn_mfma_f32_16x16x32_bf16(a1h, b0h, fac[1][0], 0, 0, 0);
                fac[1][0] = __builtin_amdgcn_mfma_f32_16x16x32_bf16(a1l, b0h, fac[1][0], 0, 0, 0);
                fac[1][1] = __builtin_amdgcn_mfma_f32_16x16x32_bf16(a1h, b1h, fac[1][1], 0, 0, 0);
                fac[1][1] = __builtin_amdgcn_mfma_f32_16x16x32_bf16(a1l, b1h, fac[1][1], 0, 0, 0);
            }
#pragma unroll
            for (int i = 0; i < 2; ++i)
#pragma unroll
                for (int jn = 0; jn < 2; ++jn)
#pragma unroll
                    for (int j = 0; j < 4; ++j) {
                        int M = bi * 64 + (mt0 + i) * 16 + ((l >> 4) << 2) + j;
                        int P = bj * 64 + (nt0 + jn) * 16 + (l & 15);
                        int id = frag_idx(M, P);
                        float v = fac[i][jn][j] - (bf2f(Xh[id]) + bf2f(Xl[id]));
                        dwrite_frag(Bqh, Bql, M, P, v);
                    }
        }
    } else {
        if (tid < MM) qbuf[tid] = qmu[tid];
        __syncthreads();
        int mt = (blk - 36) * 8 + w;   // 0..23
        float s = 0.f;
        for (int kt = 0; kt < 12; ++kt) {
            int b = ((mt * 12 + kt) * 64 + l) * 8;
            short8 h8 = *(const short8*)&Xh[b];
            short8 l8 = *(const short8*)&Xl[b];
            int kb = kt * 32 + ((l >> 4) << 3);
#pragma unroll
            for (int j = 0; j < 8; ++j)
                s += (bf2f((u16)h8[j]) + bf2f((u16)l8[j])) * qbuf[kb + j];
        }
        s += __shfl_xor(s, 16);
        s += __shfl_xor(s, 32);
        if (l < 16) cvec[mt * 16 + l] = s;
    }
}

// ---------------------------------------------------------------------------
// Main fused kernel, 64 points/block, 512 threads, 3 blocks/CU (LDS 53 KB).
__global__ void __launch_bounds__(512) main_kernel(
    const float* __restrict__ Xin,
    const u16* __restrict__ Zfh, const u16* __restrict__ Zfl,
    const float* __restrict__ z2g,
    const u16* __restrict__ Bfh, const u16* __restrict__ Bfl,
    const float* __restrict__ cvec,
    const float* __restrict__ var_p, const float* __restrict__ ls_p,
    float* __restrict__ out) {
    __shared__ u16 kh[12 * 4 * 64 * 8];   // 48 KB; first 9216 B double as patch
    __shared__ float zsq[MM];
    __shared__ float xsq[64];
    __shared__ float red[512];
    float* patch = (float*)kh;            // [64][36], dead before kh writes

    int tid = threadIdx.x;
    int np0 = blockIdx.x * 64;
    float var = var_p[0];
    float ls = ls_p[0];
    float c2 = -0.72134752044f / (ls * ls);   // -0.5*log2(e)/ls^2

    if (tid < MM) zsq[tid] = z2g[tid];
    for (int e = tid; e < 64 * 36; e += 512) {
        int pt = e / 36, c = e % 36;
        float v = 0.f;
        if (c < 25) {
            int np = np0 + pt;
            int n = np / PP, p = np % PP;
            int oi = p / 36, oj = p % 36;
            v = Xin[n * (HH * WW) + (oi + c / 5) * WW + (oj + c % 5)];
        }
        patch[e] = v;
    }
    __syncthreads();
    if (tid < 64) {
        float s = 0.f;
#pragma unroll
        for (int d = 0; d < LL; ++d) { float x = patch[tid * 36 + d]; s += x * x; }
        xsq[tid] = s;
    }
    int w = tid >> 6, l = tid & 63;

    // build patch B-frags in registers (last patch readers)
    short8 pbh[4], pbl[4];
#pragma unroll
    for (int nt = 0; nt < 4; ++nt) {
        int p = nt * 16 + (l & 15);
        int pb = p * 36 + ((l >> 4) << 3);
        float4 f0 = *(const float4*)&patch[pb];
        float4 f1 = *(const float4*)&patch[pb + 4];
        float xv[8] = {f0.x, f0.y, f0.z, f0.w, f1.x, f1.y, f1.z, f1.w};
#pragma unroll
        for (int j = 0; j < 8; ++j) {
            u16 h, lo;
            split_bf16(xv[j], h, lo);
            pbh[nt][j] = (short)h;
            pbl[nt][j] = (short)lo;
        }
    }
    __syncthreads();   // patch reads done; kh region reusable

    // phase 1: cross = Z @ patch^T (split-bf16 MFMA, 3-term)
    floatx4 acc2[3][4];
#pragma unroll
    for (int i = 0; i < 3; ++i) {
        int zt = w * 3 + i;
        short8 zah = *(const short8*)&Zfh[(zt * 64 + l) * 8];
        short8 zal = *(const short8*)&Zfl[(zt * 64 + l) * 8];
#pragma unroll
        for (int nt = 0; nt < 4; ++nt) {
            floatx4 z = {0.f, 0.f, 0.f, 0.f};
            z = __builtin_amdgcn_mfma_f32_16x16x32_bf16(zah, pbh[nt], z, 0, 0, 0);
            z = __builtin_amdgcn_mfma_f32_16x16x32_bf16(zah, pbl[nt], z, 0, 0, 0);
            z = __builtin_amdgcn_mfma_f32_16x16x32_bf16(zal, pbh[nt], z, 0, 0, 0);
            acc2[i][nt] = z;
        }
    }

    // finalize K: fp32 in regs, fold mean partials (cvec from L2), bf16 hi->LDS
    float Kreg[3][4][4];
    float mp[4] = {0.f, 0.f, 0.f, 0.f};
#pragma unroll
    for (int i = 0; i < 3; ++i) {
        int a2 = w * 3 + i;
        int u = l >> 4;
        int kt = a2 >> 1;
        int rr = 2 * (a2 & 1) + (u >> 1);
        int k0 = a2 * 16 + 4 * u;
        float4 c4 = *(const float4*)&cvec[k0];
        float cvl[4] = {c4.x, c4.y, c4.z, c4.w};
#pragma unroll
        for (int nt = 0; nt < 4; ++nt) {
            int p = nt * 16 + (l & 15);
            u16 hi[4];
#pragma unroll
            for (int j = 0; j < 4; ++j) {
                float s = zsq[k0 + j] + xsq[p] - 2.f * acc2[i][nt][j];
                float v = var * exp2f(s * c2);
                Kreg[i][nt][j] = v;
                mp[nt] += cvl[j] * v;
                hi[j] = f2bf(v);
            }
            int base = ((kt * 4 + nt) * 64 + rr * 16 + (l & 15)) * 8 + 4 * (u & 1);
            *(u32*)&kh[base]     = (u32)hi[0] | ((u32)hi[1] << 16);
            *(u32*)&kh[base + 2] = (u32)hi[2] | ((u32)hi[3] << 16);
        }
    }
#pragma unroll
    for (int nt = 0; nt < 4; ++nt) {
        mp[nt] += __shfl_xor(mp[nt], 16);
        mp[nt] += __shfl_xor(mp[nt], 32);
    }
    if (l < 16) {
#pragma unroll
        for (int nt = 0; nt < 4; ++nt) red[w * 64 + nt * 16 + l] = mp[nt];
    }
    __syncthreads();   // publishes kh AND mean partials
    if (tid < 64) {
        float s = 0.f;
#pragma unroll
        for (int ww = 0; ww < 8; ++ww) s += red[ww * 64 + tid];
        out[np0 + tid] = s;   // mean
    }

    // phase 2: acc[m][p] = sum_k Bq[m][k] K[k][p]; B split 2-term, K hi only
    floatx4 acc[3][4];
#pragma unroll
    for (int i = 0; i < 3; ++i)
#pragma unroll
        for (int nt = 0; nt < 4; ++nt) { floatx4 z = {0.f, 0.f, 0.f, 0.f}; acc[i][nt] = z; }
    for (int kt = 0; kt < 12; ++kt) {
        short8 bh[4];
#pragma unroll
        for (int nt = 0; nt < 4; ++nt)
            bh[nt] = *(const short8*)&kh[((kt * 4 + nt) * 64 + l) * 8];
#pragma unroll
        for (int i = 0; i < 3; ++i) {
            int mt = w * 3 + i;
            int ab = ((mt * 12 + kt) * 64 + l) * 8;
            short8 ah = *(const short8*)&Bfh[ab];
            short8 al = *(const short8*)&Bfl[ab];
#pragma unroll
            for (int nt = 0; nt < 4; ++nt) {
                acc[i][nt] = __builtin_amdgcn_mfma_f32_16x16x32_bf16(ah, bh[nt], acc[i][nt], 0, 0, 0);
                acc[i][nt] = __builtin_amdgcn_mfma_f32_16x16x32_bf16(al, bh[nt], acc[i][nt], 0, 0, 0);
            }
        }
    }
    __syncthreads();   // mean readers done before red reuse

    // diag epilogue: register dot (identical D-frag maps for Kreg and acc)
    float dp[4] = {0.f, 0.f, 0.f, 0.f};
#pragma unroll
    for (int i = 0; i < 3; ++i)
#pragma unroll
        for (int nt = 0; nt < 4; ++nt)
#pragma unroll
            for (int j = 0; j < 4; ++j)
                dp[nt] += Kreg[i][nt][j] * acc[i][nt][j];
#pragma unroll
    for (int nt = 0; nt < 4; ++nt) {
        dp[nt] += __shfl_xor(dp[nt], 16);
        dp[nt] += __shfl_xor(dp[nt], 32);
    }
    if (l < 16) {
#pragma unroll
        for (int nt = 0; nt < 4; ++nt) red[w * 64 + nt * 16 + l] = dp[nt];
    }
    __syncthreads();
    if (tid < 64) {
        float s = 0.f;
#pragma unroll
        for (int ww = 0; ww < 8; ++ww) s += red[ww * 64 + tid];
        out[NPTS + np0 + tid] = var + s;
    }
}

// ---------------------------------------------------------------------------
extern "C" void kernel_launch(void* const* d_in, const int* in_sizes, int n_in,
                              void* d_out, int out_size, void* d_ws, size_t ws_size,
                              hipStream_t stream) {
    const float* Xin    = (const float*)d_in[0];
    const float* Z      = (const float*)d_in[1];
    const float* q_mu   = (const float*)d_in[2];
    const float* q_sqrt = (const float*)d_in[3];
    const float* var_p  = (const float*)d_in[4];
    const float* ls_p   = (const float*)d_in[5];
    float* out = (float*)d_out;

    const size_t HB = (size_t)FRAG_N * 2;  // 294912 B per frag half-array
    char* base = (char*)d_ws;
    float* Kuu = (float*)base;                 // 2 HB; Bq frags overlay later
    u16* Bqh = (u16*)base;
    u16* Bql = (u16*)(base + HB);
    u16* Xh_a = (u16*)(base + 2 * HB);
    u16* Xl_a = (u16*)(base + 3 * HB);
    u16* Xh_b = (u16*)(base + 4 * HB);
    u16* Xl_b = (u16*)(base + 5 * HB);
    u16* Rh_a = (u16*)(base + 6 * HB);
    u16* Rl_a = (u16*)(base + 7 * HB);
    u16* Rh_b = (u16*)(base + 8 * HB);
    u16* Rl_b = (u16*)(base + 9 * HB);
    u16* Qth  = (u16*)(base + 10 * HB);
    u16* Qtl  = (u16*)(base + 11 * HB);
    char* pF = base + 12 * HB;
    u16* Zfh = (u16*)pF;
    u16* Zfl = (u16*)(pF + ZFRAG_N * 2);
    float* z2g  = (float*)(pF + ZFRAG_N * 4);
    float* cvec = z2g + MM;
    float* rsum = cvec + MM;

    // 1) prep: Kuu, rowsums, z2, Z frags, Qt frags
    prep_kernel<<<MM, 384, 0, stream>>>(Z, q_sqrt, var_p, ls_p, Kuu, rsum, z2g,
                                        Qth, Qtl, Zfh, Zfl);
    // 2) ns1: X1 elementwise | R1 = R0@R0
    ns1_kernel<<<72, 256, 0, stream>>>(Kuu, rsum, Xh_b, Xl_b, Rh_b, Rl_b);
    // 3-7) NS rounds 2..6 (5 launches; odd count: final X lands in a-slots)
    u16 *cxh = Xh_b, *cxl = Xl_b, *nxh = Xh_a, *nxl = Xl_a;
    u16 *crh = Rh_b, *crl = Rl_b, *nrh = Rh_a, *nrl = Rl_a;
    for (int it = 0; it < 5; ++it) {
        ns_kernel<<<72, 256, 0, stream>>>(cxh, cxl, crh, crl, nxh, nxl, nrh, nrl);
        u16* t;
        t = cxh; cxh = nxh; nxh = t;
        t = cxl; cxl = nxl; nxl = t;
        t = crh; crh = nrh; nrh = t;
        t = crl; crl = nrl; nrl = t;
    }
    // 8) gbq: Bq = G G^T - X (G = X Lq, panels in LDS) | cvec = X q_mu
    gbq_kernel<<<39, 512, 0, stream>>>(cxh, cxl, Qth, Qtl, q_mu, Bqh, Bql, cvec);
    // 9) main
    main_kernel<<<NPTS / 64, 512, 0, stream>>>(Xin, Zfh, Zfl, z2g, Bqh, Bql, cvec,
                                               var_p, ls_p, out);
}

// Round 7
// 197.233 us; speedup vs baseline: 1.2075x; 1.2075x over previous
//
#include <hip/hip_runtime.h>
#include <hip/hip_bf16.h>

// Problem constants
#define HH 40
#define WW 40
#define KK 5
#define PP 1296            // 36*36
#define LL 25
#define MM 384
#define NN 64
#define NPTS (NN * PP)     // 82944
#define JITTER 1e-6f

typedef unsigned short u16;
typedef unsigned int   u32;
using short8  = __attribute__((ext_vector_type(8))) short;
using floatx4 = __attribute__((ext_vector_type(4))) float;

#define FRAG_N (MM * MM)        // u16 per frag half-array (147456)
#define ZFRAG_N (24 * 64 * 8)   // 12288

// ---------------------------------------------------------------------------
// bf16 split helpers (RNE)
__device__ inline u16 f2bf(float v) {
    u32 b = __float_as_uint(v);
    return (u16)((b + 0x7FFFu + ((b >> 16) & 1u)) >> 16);
}
__device__ inline float bf2f(u16 h) { return __uint_as_float(((u32)h) << 16); }
__device__ inline void split_bf16(float v, u16& hi, u16& lo) {
    hi = f2bf(v);
    lo = f2bf(v - bf2f(hi));
}

// A-fragment linear index (u16 units) for element (m,k), HW-verified rounds 2-6.
__device__ inline int frag_idx(int m, int k) {
    return (((m >> 4) * 12 + (k >> 5)) * 64 + ((m & 15) + (((k >> 3) & 3) << 4))) * 8 + (k & 7);
}

// ---------------------------------------------------------------------------
// Split-bf16 MFMA 64x64-tile GEMM on A-frag operands: C = A . B^T_storage.
__device__ inline void frag_gemm64(const u16* __restrict__ Ah, const u16* __restrict__ Al,
                                   const u16* __restrict__ Bh, const u16* __restrict__ Bl,
                                   int bi, int bj, int w, int l, floatx4 acc[2][2]) {
    int mt0 = bi * 4 + 2 * (w & 1);
    int nt0 = bj * 4 + 2 * (w >> 1);
#pragma unroll
    for (int i = 0; i < 2; ++i)
#pragma unroll
        for (int jn = 0; jn < 2; ++jn) { floatx4 z = {0.f, 0.f, 0.f, 0.f}; acc[i][jn] = z; }
    for (int kt = 0; kt < 12; ++kt) {
        int ab0 = (((mt0 + 0) * 12 + kt) * 64 + l) * 8;
        int ab1 = (((mt0 + 1) * 12 + kt) * 64 + l) * 8;
        int bb0 = (((nt0 + 0) * 12 + kt) * 64 + l) * 8;
        int bb1 = (((nt0 + 1) * 12 + kt) * 64 + l) * 8;
        short8 a0h = *(const short8*)&Ah[ab0];
        short8 a0l = *(const short8*)&Al[ab0];
        short8 a1h = *(const short8*)&Ah[ab1];
        short8 a1l = *(const short8*)&Al[ab1];
        short8 b0h = *(const short8*)&Bh[bb0];
        short8 b0l = *(const short8*)&Bl[bb0];
        short8 b1h = *(const short8*)&Bh[bb1];
        short8 b1l = *(const short8*)&Bl[bb1];
        acc[0][0] = __builtin_amdgcn_mfma_f32_16x16x32_bf16(a0h, b0h, acc[0][0], 0, 0, 0);
        acc[0][0] = __builtin_amdgcn_mfma_f32_16x16x32_bf16(a0h, b0l, acc[0][0], 0, 0, 0);
        acc[0][0] = __builtin_amdgcn_mfma_f32_16x16x32_bf16(a0l, b0h, acc[0][0], 0, 0, 0);
        acc[0][1] = __builtin_amdgcn_mfma_f32_16x16x32_bf16(a0h, b1h, acc[0][1], 0, 0, 0);
        acc[0][1] = __builtin_amdgcn_mfma_f32_16x16x32_bf16(a0h, b1l, acc[0][1], 0, 0, 0);
        acc[0][1] = __builtin_amdgcn_mfma_f32_16x16x32_bf16(a0l, b1h, acc[0][1], 0, 0, 0);
        acc[1][0] = __builtin_amdgcn_mfma_f32_16x16x32_bf16(a1h, b0h, acc[1][0], 0, 0, 0);
        acc[1][0] = __builtin_amdgcn_mfma_f32_16x16x32_bf16(a1h, b0l, acc[1][0], 0, 0, 0);
        acc[1][0] = __builtin_amdgcn_mfma_f32_16x16x32_bf16(a1l, b0h, acc[1][0], 0, 0, 0);
        acc[1][1] = __builtin_amdgcn_mfma_f32_16x16x32_bf16(a1h, b1h, acc[1][1], 0, 0, 0);
        acc[1][1] = __builtin_amdgcn_mfma_f32_16x16x32_bf16(a1h, b1l, acc[1][1], 0, 0, 0);
        acc[1][1] = __builtin_amdgcn_mfma_f32_16x16x32_bf16(a1l, b1h, acc[1][1], 0, 0, 0);
    }
}

__device__ inline void dwrite_frag(u16* __restrict__ Oh, u16* __restrict__ Ol,
                                   int m, int p, float v) {
    int idx = frag_idx(m, p);
    u16 hi, lo;
    split_bf16(v, hi, lo);
    Oh[idx] = hi; Ol[idx] = lo;
}

// R0 = I - alpha*Kuu fragment built on the fly (R0 symmetric)
__device__ inline void load_r0(const float* __restrict__ Kuu, float alpha,
                               int row, int kt, int l, short8& h8, short8& l8) {
    int kb = kt * 32 + ((l >> 4) << 3);
    const float* p = &Kuu[row * MM + kb];
    float4 f0 = *(const float4*)p;
    float4 f1 = *(const float4*)(p + 4);
    float vv[8] = {f0.x, f0.y, f0.z, f0.w, f1.x, f1.y, f1.z, f1.w};
#pragma unroll
    for (int j = 0; j < 8; ++j) {
        float r = ((row == kb + j) ? 1.f : 0.f) - alpha * vv[j];
        u16 h, lo;
        split_bf16(r, h, lo);
        h8[j] = (short)h; l8[j] = (short)lo;
    }
}

// ---------------------------------------------------------------------------
// Launch 1: Kuu + rowsums + z2 + Z frags + Q frags (A-frag of tril(q_sqrt)).
__global__ void __launch_bounds__(384) prep_kernel(
    const float* __restrict__ Z, const float* __restrict__ q_sqrt,
    const float* __restrict__ var_p, const float* __restrict__ ls_p,
    float* __restrict__ Kuu, float* __restrict__ rsum, float* __restrict__ z2g,
    u16* __restrict__ Qh, u16* __restrict__ Ql,
    u16* __restrict__ Zfh, u16* __restrict__ Zfl) {
    __shared__ float Zs[LL];
    __shared__ float red[384];
    int r = blockIdx.x, tid = threadIdx.x;
    if (tid < LL) Zs[tid] = Z[r * LL + tid];
    __syncthreads();
    float var = var_p[0];
    float ls = ls_p[0];
    float c0 = -0.5f / (ls * ls);
    float s = 0.f;
#pragma unroll
    for (int d = 0; d < LL; ++d) {
        float dd = Zs[d] - Z[tid * LL + d];
        s += dd * dd;
    }
    float v = var * expf(c0 * s);
    if (tid == r) v += JITTER;
    Kuu[r * MM + tid] = v;
    red[tid] = v;
    __syncthreads();
    if (tid < 128) red[tid] += red[tid + 256];
    __syncthreads();
    for (int o = 128; o > 0; o >>= 1) {
        if (tid < o) red[tid] += red[tid + o];
        __syncthreads();
    }
    if (tid == 0) {
        rsum[r] = red[0];
        float t = 0.f;
#pragma unroll
        for (int d = 0; d < LL; ++d) t += Zs[d] * Zs[d];
        z2g[r] = t;
    }
    // Q frags: one element per thread (384*384 == FRAG_N)
    {
        int o = r * MM + tid;
        int j = o & 7, ln = (o >> 3) & 63, kt = (o >> 9) % 12, mt = o / 6144;
        int m = mt * 16 + (ln & 15);
        int k = kt * 32 + ((ln >> 4) << 3) + j;
        float qv = (k <= m) ? q_sqrt[m * MM + k] : 0.f;
        u16 h, lo;
        split_bf16(qv, h, lo);
        Qh[o] = h; Ql[o] = lo;
        if (o < ZFRAG_N) {
            int zt = o >> 9;
            int mz = zt * 16 + (ln & 15);
            int kd = ((ln >> 4) << 3) + j;
            float zv = (kd < LL) ? Z[mz * LL + kd] : 0.f;
            split_bf16(zv, h, lo);
            Zfh[o] = h; Zfl[o] = lo;
        }
    }
}

// ---------------------------------------------------------------------------
// Launch 2: blocks 0-35: X1 = alpha*(2I - alpha*Kuu); 36-71: R1 = R0@R0;
//           72-107: SK = Q@Q^T - Kuu.
__global__ void __launch_bounds__(256) ns1_kernel(
    const float* __restrict__ Kuu, const float* __restrict__ rsum,
    const u16* __restrict__ Qh, const u16* __restrict__ Ql,
    u16* __restrict__ Xh, u16* __restrict__ Xl,
    u16* __restrict__ Rh, u16* __restrict__ Rl,
    u16* __restrict__ SKh, u16* __restrict__ SKl) {
    __shared__ float red[256];
    int tid = threadIdx.x, blk = blockIdx.x;
    int w = tid >> 6, l = tid & 63;
    float alpha = 0.f;
    if (blk < 72) {
        float v0 = rsum[tid];
        if (tid < 128) v0 = fmaxf(v0, rsum[tid + 256]);
        red[tid] = v0;
        __syncthreads();
        for (int o = 128; o > 0; o >>= 1) {
            if (tid < o) red[tid] = fmaxf(red[tid], red[tid + o]);
            __syncthreads();
        }
        alpha = 1.0f / red[0];
    }
    if (blk < 36) {
        float a2 = alpha * alpha;
        for (int o = blk * 256 + tid; o < FRAG_N; o += 36 * 256) {
            int j = o & 7, ln = (o >> 3) & 63, kt = (o >> 9) % 12, mt = o / 6144;
            int m = mt * 16 + (ln & 15);
            int k = kt * 32 + ((ln >> 4) << 3) + j;
            float v = ((m == k) ? 2.f * alpha : 0.f) - a2 * Kuu[m * MM + k];
            u16 h, lo;
            split_bf16(v, h, lo);
            Xh[o] = h; Xl[o] = lo;
        }
    } else if (blk < 72) {
        int tile = blk - 36;
        int bi = tile / 6, bj = tile % 6;
        int mt0 = bi * 4 + 2 * (w & 1), nt0 = bj * 4 + 2 * (w >> 1);
        floatx4 acc[2][2];
#pragma unroll
        for (int i = 0; i < 2; ++i)
#pragma unroll
            for (int jn = 0; jn < 2; ++jn) { floatx4 z = {0.f,0.f,0.f,0.f}; acc[i][jn] = z; }
        for (int kt = 0; kt < 12; ++kt) {
            short8 a0h, a0l, a1h, a1l, b0h, b0l, b1h, b1l;
            load_r0(Kuu, alpha, (mt0 + 0) * 16 + (l & 15), kt, l, a0h, a0l);
            load_r0(Kuu, alpha, (mt0 + 1) * 16 + (l & 15), kt, l, a1h, a1l);
            load_r0(Kuu, alpha, (nt0 + 0) * 16 + (l & 15), kt, l, b0h, b0l);
            load_r0(Kuu, alpha, (nt0 + 1) * 16 + (l & 15), kt, l, b1h, b1l);
            acc[0][0] = __builtin_amdgcn_mfma_f32_16x16x32_bf16(a0h, b0h, acc[0][0], 0, 0, 0);
            acc[0][0] = __builtin_amdgcn_mfma_f32_16x16x32_bf16(a0h, b0l, acc[0][0], 0, 0, 0);
            acc[0][0] = __builtin_amdgcn_mfma_f32_16x16x32_bf16(a0l, b0h, acc[0][0], 0, 0, 0);
            acc[0][1] = __builtin_amdgcn_mfma_f32_16x16x32_bf16(a0h, b1h, acc[0][1], 0, 0, 0);
            acc[0][1] = __builtin_amdgcn_mfma_f32_16x16x32_bf16(a0h, b1l, acc[0][1], 0, 0, 0);
            acc[0][1] = __builtin_amdgcn_mfma_f32_16x16x32_bf16(a0l, b1h, acc[0][1], 0, 0, 0);
            acc[1][0] = __builtin_amdgcn_mfma_f32_16x16x32_bf16(a1h, b0h, acc[1][0], 0, 0, 0);
            acc[1][0] = __builtin_amdgcn_mfma_f32_16x16x32_bf16(a1h, b0l, acc[1][0], 0, 0, 0);
            acc[1][0] = __builtin_amdgcn_mfma_f32_16x16x32_bf16(a1l, b0h, acc[1][0], 0, 0, 0);
            acc[1][1] = __builtin_amdgcn_mfma_f32_16x16x32_bf16(a1h, b1h, acc[1][1], 0, 0, 0);
            acc[1][1] = __builtin_amdgcn_mfma_f32_16x16x32_bf16(a1h, b1l, acc[1][1], 0, 0, 0);
            acc[1][1] = __builtin_amdgcn_mfma_f32_16x16x32_bf16(a1l, b1h, acc[1][1], 0, 0, 0);
        }
#pragma unroll
        for (int i = 0; i < 2; ++i)
#pragma unroll
            for (int jn = 0; jn < 2; ++jn)
#pragma unroll
                for (int j = 0; j < 4; ++j) {
                    int m = (mt0 + i) * 16 + ((l >> 4) << 2) + j;
                    int p = (nt0 + jn) * 16 + (l & 15);
                    dwrite_frag(Rh, Rl, m, p, acc[i][jn][j]);
                }
    } else {
        int tile = blk - 72;
        int bi = tile / 6, bj = tile % 6;
        floatx4 acc[2][2];
        frag_gemm64(Qh, Ql, Qh, Ql, bi, bj, w, l, acc);
        int mt0 = bi * 4 + 2 * (w & 1), nt0 = bj * 4 + 2 * (w >> 1);
#pragma unroll
        for (int i = 0; i < 2; ++i)
#pragma unroll
            for (int jn = 0; jn < 2; ++jn)
#pragma unroll
                for (int j = 0; j < 4; ++j) {
                    int m = (mt0 + i) * 16 + ((l >> 4) << 2) + j;
                    int p = (nt0 + jn) * 16 + (l & 15);
                    dwrite_frag(SKh, SKl, m, p, acc[i][jn][j] - Kuu[m * MM + p]);
                }
    }
}

// ---------------------------------------------------------------------------
// NS rounds: blocks 0-35: X' = X + X@R ; 36-71: R' = R@R
__global__ void __launch_bounds__(256) ns_kernel(
    const u16* __restrict__ cxh, const u16* __restrict__ cxl,
    const u16* __restrict__ crh, const u16* __restrict__ crl,
    u16* __restrict__ nxh, u16* __restrict__ nxl,
    u16* __restrict__ nrh, u16* __restrict__ nrl) {
    int blk = blockIdx.x, tid = threadIdx.x;
    bool isX = (blk < 36);
    int tile = isX ? blk : blk - 36;
    int bi = tile / 6, bj = tile % 6;
    int w = tid >> 6, l = tid & 63;
    floatx4 acc[2][2];
    frag_gemm64(isX ? cxh : crh, isX ? cxl : crl, crh, crl, bi, bj, w, l, acc);
    int mt0 = bi * 4 + 2 * (w & 1), nt0 = bj * 4 + 2 * (w >> 1);
    u16* Oh = isX ? nxh : nrh;
    u16* Ol = isX ? nxl : nrl;
#pragma unroll
    for (int i = 0; i < 2; ++i)
#pragma unroll
        for (int jn = 0; jn < 2; ++jn)
#pragma unroll
            for (int j = 0; j < 4; ++j) {
                int m = (mt0 + i) * 16 + ((l >> 4) << 2) + j;
                int p = (nt0 + jn) * 16 + (l & 15);
                float v = acc[i][jn][j];
                if (isX) {
                    int id = frag_idx(m, p);
                    v += bf2f(cxh[id]) + bf2f(cxl[id]);
                }
                dwrite_frag(Oh, Ol, m, p, v);
            }
}

// ---------------------------------------------------------------------------
// Launch 8: blocks 0-35: Y = X @ SK ; blocks 36-41: cvec = X @ q_mu
__global__ void __launch_bounds__(256) y_kernel(
    const u16* __restrict__ Xh, const u16* __restrict__ Xl,
    const u16* __restrict__ SKh, const u16* __restrict__ SKl,
    const float* __restrict__ qmu,
    u16* __restrict__ Yh, u16* __restrict__ Yl, float* __restrict__ cvec) {
    __shared__ float q[MM];
    int tid = threadIdx.x, blk = blockIdx.x;
    int w = tid >> 6, l = tid & 63;
    if (blk < 36) {
        int bi = blk / 6, bj = blk % 6;
        floatx4 acc[2][2];
        frag_gemm64(Xh, Xl, SKh, SKl, bi, bj, w, l, acc);
        int mt0 = bi * 4 + 2 * (w & 1), nt0 = bj * 4 + 2 * (w >> 1);
#pragma unroll
        for (int i = 0; i < 2; ++i)
#pragma unroll
            for (int jn = 0; jn < 2; ++jn)
#pragma unroll
                for (int j = 0; j < 4; ++j) {
                    int m = (mt0 + i) * 16 + ((l >> 4) << 2) + j;
                    int p = (nt0 + jn) * 16 + (l & 15);
                    dwrite_frag(Yh, Yl, m, p, acc[i][jn][j]);
                }
    } else {
        if (tid < MM) q[tid] = qmu[tid];
        if (tid + 256 < MM) q[tid + 256] = qmu[tid + 256];
        __syncthreads();
        int mt = (blk - 36) * 4 + w;
        float s = 0.f;
        for (int kt = 0; kt < 12; ++kt) {
            int b = ((mt * 12 + kt) * 64 + l) * 8;
            short8 h8 = *(const short8*)&Xh[b];
            short8 l8 = *(const short8*)&Xl[b];
            int kb = kt * 32 + ((l >> 4) << 3);
#pragma unroll
            for (int j = 0; j < 8; ++j)
                s += (bf2f((u16)h8[j]) + bf2f((u16)l8[j])) * q[kb + j];
        }
        s += __shfl_xor(s, 16);
        s += __shfl_xor(s, 32);
        if (l < 16) cvec[mt * 16 + l] = s;
    }
}

// Launch 9: Bq = Y @ X
__global__ void __launch_bounds__(256) bq_kernel(
    const u16* __restrict__ Yh, const u16* __restrict__ Yl,
    const u16* __restrict__ Xh, const u16* __restrict__ Xl,
    u16* __restrict__ Bh, u16* __restrict__ Bl) {
    int blk = blockIdx.x, tid = threadIdx.x;
    int bi = blk / 6, bj = blk % 6;
    int w = tid >> 6, l = tid & 63;
    floatx4 acc[2][2];
    frag_gemm64(Yh, Yl, Xh, Xl, bi, bj, w, l, acc);
    int mt0 = bi * 4 + 2 * (w & 1), nt0 = bj * 4 + 2 * (w >> 1);
#pragma unroll
    for (int i = 0; i < 2; ++i)
#pragma unroll
        for (int jn = 0; jn < 2; ++jn)
#pragma unroll
            for (int j = 0; j < 4; ++j) {
                int m = (mt0 + i) * 16 + ((l >> 4) << 2) + j;
                int p = (nt0 + jn) * 16 + (l & 15);
                dwrite_frag(Bh, Bl, m, p, acc[i][jn][j]);
            }
}

// ---------------------------------------------------------------------------
// Main fused kernel, 128 points/block, 512 threads (halves per-point Bq L2 traffic).
__global__ void __launch_bounds__(512) main_kernel(
    const float* __restrict__ Xin,
    const u16* __restrict__ Zfh, const u16* __restrict__ Zfl,
    const float* __restrict__ z2g,
    const u16* __restrict__ Bfh, const u16* __restrict__ Bfl,
    const float* __restrict__ cvec,
    const float* __restrict__ var_p, const float* __restrict__ ls_p,
    float* __restrict__ out) {
    __shared__ u16 kh[12 * 8 * 64 * 8];   // 96 KB: B-frag K tile (hi)
    __shared__ float patch[128 * 36];     // 18 KB
    __shared__ float zsq[MM];
    __shared__ float xsq[128];
    __shared__ float red[1024];

    int tid = threadIdx.x;
    int np0 = blockIdx.x * 128;
    float var = var_p[0];
    float ls = ls_p[0];
    float c2 = -0.72134752044f / (ls * ls);   // -0.5*log2(e)/ls^2

    if (tid < MM) zsq[tid] = z2g[tid];
    for (int e = tid; e < 128 * 36; e += 512) {
        int pt = e / 36, c = e % 36;
        float v = 0.f;
        if (c < 25) {
            int np = np0 + pt;
            int n = np / PP, p = np % PP;
            int oi = p / 36, oj = p % 36;
            v = Xin[n * (HH * WW) + (oi + c / 5) * WW + (oj + c % 5)];
        }
        patch[e] = v;
    }
    __syncthreads();
    if (tid < 128) {
        float s = 0.f;
#pragma unroll
        for (int d = 0; d < LL; ++d) { float x = patch[tid * 36 + d]; s += x * x; }
        xsq[tid] = s;
    }
    __syncthreads();

    int w = tid >> 6, l = tid & 63;
    int u = l >> 4;

    u32 kpk[3][8][2];                     // packed bf16 K values (left factor)
    float mp[8] = {0.f, 0.f, 0.f, 0.f, 0.f, 0.f, 0.f, 0.f};

    // phase 1 in two 64-point halves: cross = Z @ patch^T, then K finalize.
#pragma unroll
    for (int h = 0; h < 2; ++h) {
        short8 pbh[4], pbl[4];
#pragma unroll
        for (int nt = 0; nt < 4; ++nt) {
            int p = h * 64 + nt * 16 + (l & 15);
            int pb = p * 36 + (u << 3);
            float4 f0 = *(const float4*)&patch[pb];
            float4 f1 = *(const float4*)&patch[pb + 4];
            float xv[8] = {f0.x, f0.y, f0.z, f0.w, f1.x, f1.y, f1.z, f1.w};
#pragma unroll
            for (int j = 0; j < 8; ++j) {
                u16 hh, lo;
                split_bf16(xv[j], hh, lo);
                pbh[nt][j] = (short)hh;
                pbl[nt][j] = (short)lo;
            }
        }
        floatx4 acc2[3][4];
#pragma unroll
        for (int i = 0; i < 3; ++i) {
            int zt = w * 3 + i;
            short8 zah = *(const short8*)&Zfh[(zt * 64 + l) * 8];
            short8 zal = *(const short8*)&Zfl[(zt * 64 + l) * 8];
#pragma unroll
            for (int nt = 0; nt < 4; ++nt) {
                floatx4 z = {0.f, 0.f, 0.f, 0.f};
                z = __builtin_amdgcn_mfma_f32_16x16x32_bf16(zah, pbh[nt], z, 0, 0, 0);
                z = __builtin_amdgcn_mfma_f32_16x16x32_bf16(zah, pbl[nt], z, 0, 0, 0);
                z = __builtin_amdgcn_mfma_f32_16x16x32_bf16(zal, pbh[nt], z, 0, 0, 0);
                acc2[i][nt] = z;
            }
        }
        // finalize K for this half
#pragma unroll
        for (int i = 0; i < 3; ++i) {
            int a2 = w * 3 + i;
            int kt = a2 >> 1;
            int rr = 2 * (a2 & 1) + (u >> 1);
            int k0 = a2 * 16 + 4 * u;
            float4 c4 = *(const float4*)&cvec[k0];
            float cvl[4] = {c4.x, c4.y, c4.z, c4.w};
#pragma unroll
            for (int nt = 0; nt < 4; ++nt) {
                int ntg = h * 4 + nt;
                int p = h * 64 + nt * 16 + (l & 15);
                u16 hi[4];
#pragma unroll
                for (int j = 0; j < 4; ++j) {
                    float s = zsq[k0 + j] + xsq[p] - 2.f * acc2[i][nt][j];
                    float v = var * exp2f(s * c2);
                    mp[ntg] += cvl[j] * v;
                    hi[j] = f2bf(v);
                }
                u32 p0 = (u32)hi[0] | ((u32)hi[1] << 16);
                u32 p1 = (u32)hi[2] | ((u32)hi[3] << 16);
                int base = ((kt * 8 + ntg) * 64 + rr * 16 + (l & 15)) * 8 + 4 * (u & 1);
                *(u32*)&kh[base]     = p0;
                *(u32*)&kh[base + 2] = p1;
                kpk[i][ntg][0] = p0;
                kpk[i][ntg][1] = p1;
            }
        }
    }

    // mean partials: wave-reduce, cross-wave via red
#pragma unroll
    for (int nt = 0; nt < 8; ++nt) {
        mp[nt] += __shfl_xor(mp[nt], 16);
        mp[nt] += __shfl_xor(mp[nt], 32);
    }
    if (l < 16) {
#pragma unroll
        for (int nt = 0; nt < 8; ++nt) red[w * 128 + nt * 16 + l] = mp[nt];
    }
    __syncthreads();   // publishes kh AND mean partials
    if (tid < 128) {
        float s = 0.f;
#pragma unroll
        for (int ww = 0; ww < 8; ++ww) s += red[ww * 128 + tid];
        out[np0 + tid] = s;   // mean
    }

    // phase 2: acc[m][p] = sum_k Bq[m][k] K[k][p]; B split 2-term, K hi only
    floatx4 acc[3][8];
#pragma unroll
    for (int i = 0; i < 3; ++i)
#pragma unroll
        for (int nt = 0; nt < 8; ++nt) { floatx4 z = {0.f, 0.f, 0.f, 0.f}; acc[i][nt] = z; }
    for (int kt = 0; kt < 12; ++kt) {
        short8 bh[8];
#pragma unroll
        for (int nt = 0; nt < 8; ++nt)
            bh[nt] = *(const short8*)&kh[((kt * 8 + nt) * 64 + l) * 8];
#pragma unroll
        for (int i = 0; i < 3; ++i) {
            int mt = w * 3 + i;
            int ab = ((mt * 12 + kt) * 64 + l) * 8;
            short8 ah = *(const short8*)&Bfh[ab];
            short8 al = *(const short8*)&Bfl[ab];
#pragma unroll
            for (int nt = 0; nt < 8; ++nt) {
                acc[i][nt] = __builtin_amdgcn_mfma_f32_16x16x32_bf16(ah, bh[nt], acc[i][nt], 0, 0, 0);
                acc[i][nt] = __builtin_amdgcn_mfma_f32_16x16x32_bf16(al, bh[nt], acc[i][nt], 0, 0, 0);
            }
        }
    }
    __syncthreads();   // mean readers done before red reuse

    // diag epilogue: register dot; left factor = K hi (same D-frag map)
    float dp[8] = {0.f, 0.f, 0.f, 0.f, 0.f, 0.f, 0.f, 0.f};
#pragma unroll
    for (int i = 0; i < 3; ++i)
#pragma unroll
        for (int nt = 0; nt < 8; ++nt) {
            float kv0 = bf2f((u16)(kpk[i][nt][0] & 0xFFFFu));
            float kv1 = bf2f((u16)(kpk[i][nt][0] >> 16));
            float kv2 = bf2f((u16)(kpk[i][nt][1] & 0xFFFFu));
            float kv3 = bf2f((u16)(kpk[i][nt][1] >> 16));
            dp[nt] += kv0 * acc[i][nt][0] + kv1 * acc[i][nt][1]
                    + kv2 * acc[i][nt][2] + kv3 * acc[i][nt][3];
        }
#pragma unroll
    for (int nt = 0; nt < 8; ++nt) {
        dp[nt] += __shfl_xor(dp[nt], 16);
        dp[nt] += __shfl_xor(dp[nt], 32);
    }
    if (l < 16) {
#pragma unroll
        for (int nt = 0; nt < 8; ++nt) red[w * 128 + nt * 16 + l] = dp[nt];
    }
    __syncthreads();
    if (tid < 128) {
        float s = 0.f;
#pragma unroll
        for (int ww = 0; ww < 8; ++ww) s += red[ww * 128 + tid];
        out[NPTS + np0 + tid] = var + s;
    }
}

// ---------------------------------------------------------------------------
extern "C" void kernel_launch(void* const* d_in, const int* in_sizes, int n_in,
                              void* d_out, int out_size, void* d_ws, size_t ws_size,
                              hipStream_t stream) {
    const float* Xin    = (const float*)d_in[0];
    const float* Z      = (const float*)d_in[1];
    const float* q_mu   = (const float*)d_in[2];
    const float* q_sqrt = (const float*)d_in[3];
    const float* var_p  = (const float*)d_in[4];
    const float* ls_p   = (const float*)d_in[5];
    float* out = (float*)d_out;

    const size_t HB = (size_t)FRAG_N * 2;  // 294912 B per frag half-array
    char* base = (char*)d_ws;
    float* Kuu = (float*)base;                 // 2 HB; Bq frags overlay later
    u16* Bqh = (u16*)base;
    u16* Bql = (u16*)(base + HB);
    u16* Xh_a = (u16*)(base + 2 * HB);
    u16* Xl_a = (u16*)(base + 3 * HB);
    u16* Xh_b = (u16*)(base + 4 * HB);
    u16* Xl_b = (u16*)(base + 5 * HB);
    u16* Rh_a = (u16*)(base + 6 * HB);
    u16* Rl_a = (u16*)(base + 7 * HB);
    u16* Rh_b = (u16*)(base + 8 * HB);
    u16* Rl_b = (u16*)(base + 9 * HB);
    u16* Qh   = (u16*)(base + 10 * HB);        // Q frags; Y overlays later
    u16* Ql   = (u16*)(base + 11 * HB);
    u16* Yh = Qh;
    u16* Yl = Ql;
    u16* SKh  = (u16*)(base + 12 * HB);
    u16* SKl  = (u16*)(base + 13 * HB);
    char* pF = base + 14 * HB;
    u16* Zfh = (u16*)pF;
    u16* Zfl = (u16*)(pF + ZFRAG_N * 2);
    float* z2g  = (float*)(pF + ZFRAG_N * 4);
    float* cvec = z2g + MM;
    float* rsum = cvec + MM;

    // 1) prep: Kuu, rowsums, z2, Z frags, Q frags
    prep_kernel<<<MM, 384, 0, stream>>>(Z, q_sqrt, var_p, ls_p, Kuu, rsum, z2g,
                                        Qh, Ql, Zfh, Zfl);
    // 2) ns1: X1 elementwise | R1 = R0@R0 | SK = QQ^T - Kuu
    ns1_kernel<<<108, 256, 0, stream>>>(Kuu, rsum, Qh, Ql,
                                        Xh_b, Xl_b, Rh_b, Rl_b, SKh, SKl);
    // 3-7) NS rounds 2..6 (5 launches; final X lands in a-slots)
    u16 *cxh = Xh_b, *cxl = Xl_b, *nxh = Xh_a, *nxl = Xl_a;
    u16 *crh = Rh_b, *crl = Rl_b, *nrh = Rh_a, *nrl = Rl_a;
    for (int it = 0; it < 5; ++it) {
        ns_kernel<<<72, 256, 0, stream>>>(cxh, cxl, crh, crl, nxh, nxl, nrh, nrl);
        u16* t;
        t = cxh; cxh = nxh; nxh = t;
        t = cxl; cxl = nxl; nxl = t;
        t = crh; crh = nrh; nrh = t;
        t = crl; crl = nrl; nrl = t;
    }
    // 8) Y = X@SK | cvec = X@q_mu
    y_kernel<<<42, 256, 0, stream>>>(cxh, cxl, SKh, SKl, q_mu, Yh, Yl, cvec);
    // 9) Bq = Y@X (into Kuu region)
    bq_kernel<<<36, 256, 0, stream>>>(Yh, Yl, cxh, cxl, Bqh, Bql);
    // 10) main (128 points/block)
    main_kernel<<<NPTS / 128, 512, 0, stream>>>(Xin, Zfh, Zfl, z2g, Bqh, Bql, cvec,
                                                var_p, ls_p, out);
}